// Round 3
// baseline (186.407 us; speedup 1.0000x reference)
//
#include <hip/hip_runtime.h>

// CRF NLL, round 12c: in-register MFMA recursion (identical to R12b;
// resubmitted after an infra-only container failure).
//
// Trick: replicate the batch across the 16 MFMA columns and compute
//   C[to][j] = sum_from M^T[to][from] * E[from]    (identical for all j)
// with v_mfma_f32_16x16x32_f16.  Under the tag relabeling
//   tag(tt, 4g+r) = 16g + 4tt + r          (g = lane>>4, r = reg)
// the D layout (col=lane&15, row=(lane>>4)*4+reg) coincides with the
// B-operand layout (col=lane&15, k=(lane>>4)*8+j), so each step's output
// fragments are produced exactly where the next step's MFMA consumes them:
// no LDS round trip and no cross-lane ops on the serial chain.
//
// fe = exp(feat) stays in the old lane=tag layout (1 exp2/step) and crosses
// into fragment layout via a small LDS ring written 4 steps ahead (off the
// chain; read back as 2 uniform-address ds_read_b128 broadcasts).
// Rescale logic (exact same-step pow2 scale, tag-0 exponent representative,
// ksum bookkeeping) is identical to R11.
#define BB 512
#define SS 512
#define TT 64
#define START_TAG 62
#define STOP_TAG 63

#define LOG2E 1.4426950408889634f
#define LN2   0.6931471805599453f

typedef _Float16 h2 __attribute__((ext_vector_type(2)));
typedef _Float16 h8 __attribute__((ext_vector_type(8)));
typedef float    f4 __attribute__((ext_vector_type(4)));

__device__ __forceinline__ h2 pkrtz(float a, float b) {
    return __builtin_bit_cast(h2, __builtin_amdgcn_cvt_pkrtz(a, b));
}

__global__ void __launch_bounds__(128)
__attribute__((amdgpu_waves_per_eu(1, 1))) crf_main(
    const float* __restrict__ feats, const int* __restrict__ mask,
    const int* __restrict__ tags, const float* __restrict__ trans,
    float* __restrict__ out)
{
    const int b    = blockIdx.x;
    const int tid  = threadIdx.x;
    const int lane = tid & 63;

    const float* frow = feats + (size_t)b * SS * TT;
    const int*   mrow = mask + b * SS;

    // fe ring: 8 rows of 64 fp16 (1 KiB); row s holds exp(feats[b][s][t])
    __shared__ __align__(16) _Float16 febuf[8][TT];

    if (tid < 64) {
        // ---------------- forward (log partition), wave 0 ----------------
        const int g  = lane >> 4;   // k-group / slot-group 0..3
        const int cg = lane & 15;   // replicated column index

        int cnt = 0;
        #pragma unroll
        for (int s = lane; s < SS; s += 64) cnt += (mrow[s] != 0);
        #pragma unroll
        for (int off = 32; off; off >>= 1) cnt += __shfl_xor(cnt, off);
        const int len = cnt;                      // in [SS/2, SS]

        // A fragments: A[tt][kc], lane holds row i = cg, k = 8g..8g+7 of the
        // kc-th K=32 chunk.  Value = exp(trans[tag_in][tag_out]) with
        //   tag_in  = 16g + 8kc + j
        //   tag_out = 16*(cg>>2) + 4tt + (cg&3)
        const int to_base   = 16 * (cg >> 2) + (cg & 3);
        const int from_base = 16 * g;
        h8 A[4][2];
        #pragma unroll
        for (int tt = 0; tt < 4; ++tt)
            #pragma unroll
            for (int kc = 0; kc < 2; ++kc)
                #pragma unroll
                for (int j = 0; j < 8; ++j)
                    A[tt][kc][j] = (_Float16)__builtin_amdgcn_exp2f(
                        trans[(from_base + 8 * kc + j) * TT
                              + (to_base + 4 * tt)] * LOG2E);

        // init: P0[t] = f[0,t] + trans[START,t];  E = e^(P0-offs), slot order:
        // lane holds slots 16g..16g+15 (B0 = slots 0..7, B1 = 8..15 of group)
        const float offs = frow[0] + trans[START_TAG * TT + 0];  // wave-uniform
        h8 B0, B1;
        #pragma unroll
        for (int sl = 0; sl < 8; ++sl) {
            const int t0 = 16 * g + sl, t1 = t0 + 8;
            B0[sl] = (_Float16)__builtin_amdgcn_exp2f(
                (frow[t0] + trans[START_TAG * TT + t0] - offs) * LOG2E);
            B1[sl] = (_Float16)__builtin_amdgcn_exp2f(
                (frow[t1] + trans[START_TAG * TT + t1] - offs) * LOG2E);
        }
        int ksum = 0;
        const f4 Z = {0.f, 0.f, 0.f, 0.f};

        // 8-deep raw-feat ring feeding the fe LDS ring (rows s..s+7, s=1)
        float fr[8];
        #pragma unroll
        for (int j = 0; j < 8; ++j) {
            int r = 1 + j; if (r > SS - 1) r = SS - 1;
            fr[j] = frow[(size_t)r * TT + lane];
        }
        // prologue: fe rows for steps 1..4
        #pragma unroll
        for (int j = 0; j < 4; ++j)
            febuf[(1 + j) & 7][lane] =
                (_Float16)__builtin_amdgcn_exp2f(fr[j] * LOG2E);

        auto step = [&](int row) {
            // fe for this step: uniform within each 16-lane group (broadcast)
            const _Float16* fb = &febuf[row & 7][16 * g];
            const h8 fe0 = *(const h8*)(fb);
            const h8 fe1 = *(const h8*)(fb + 8);
            // D = M^T * E   (4 to-tiles x 2 k-chunks)
            f4 d0 = __builtin_amdgcn_mfma_f32_16x16x32_f16(A[0][0], B0, Z, 0, 0, 0);
            f4 d1 = __builtin_amdgcn_mfma_f32_16x16x32_f16(A[1][0], B0, Z, 0, 0, 0);
            f4 d2 = __builtin_amdgcn_mfma_f32_16x16x32_f16(A[2][0], B0, Z, 0, 0, 0);
            f4 d3 = __builtin_amdgcn_mfma_f32_16x16x32_f16(A[3][0], B0, Z, 0, 0, 0);
            d0 = __builtin_amdgcn_mfma_f32_16x16x32_f16(A[0][1], B1, d0, 0, 0, 0);
            d1 = __builtin_amdgcn_mfma_f32_16x16x32_f16(A[1][1], B1, d1, 0, 0, 0);
            d2 = __builtin_amdgcn_mfma_f32_16x16x32_f16(A[2][1], B1, d2, 0, 0, 0);
            d3 = __builtin_amdgcn_mfma_f32_16x16x32_f16(A[3][1], B1, d3, 0, 0, 0);
            // exact pow2 rescale, representative = tag 0 (d0 reg0, lane 0)
            const int eb = (__builtin_amdgcn_readfirstlane(
                                __float_as_int(d0[0])) >> 23) & 0xff;
            ksum += eb - 127;
            const float sc = __int_as_float((254 - eb) << 23);
            // E' = (D*sc) * fe, packed fp16; slot = 4*tt + reg
            const h2 p0 = pkrtz(d0[0] * sc, d0[1] * sc);
            const h2 p1 = pkrtz(d0[2] * sc, d0[3] * sc);
            const h2 p2 = pkrtz(d1[0] * sc, d1[1] * sc);
            const h2 p3 = pkrtz(d1[2] * sc, d1[3] * sc);
            const h2 p4 = pkrtz(d2[0] * sc, d2[1] * sc);
            const h2 p5 = pkrtz(d2[2] * sc, d2[3] * sc);
            const h2 p6 = pkrtz(d3[0] * sc, d3[1] * sc);
            const h2 p7 = pkrtz(d3[2] * sc, d3[3] * sc);
            const h2 q0 = p0 * __builtin_shufflevector(fe0, fe0, 0, 1);
            const h2 q1 = p1 * __builtin_shufflevector(fe0, fe0, 2, 3);
            const h2 q2 = p2 * __builtin_shufflevector(fe0, fe0, 4, 5);
            const h2 q3 = p3 * __builtin_shufflevector(fe0, fe0, 6, 7);
            const h2 q4 = p4 * __builtin_shufflevector(fe1, fe1, 0, 1);
            const h2 q5 = p5 * __builtin_shufflevector(fe1, fe1, 2, 3);
            const h2 q6 = p6 * __builtin_shufflevector(fe1, fe1, 4, 5);
            const h2 q7 = p7 * __builtin_shufflevector(fe1, fe1, 6, 7);
            B0 = __builtin_shufflevector(
                     __builtin_shufflevector(q0, q1, 0, 1, 2, 3),
                     __builtin_shufflevector(q2, q3, 0, 1, 2, 3),
                     0, 1, 2, 3, 4, 5, 6, 7);
            B1 = __builtin_shufflevector(
                     __builtin_shufflevector(q4, q5, 0, 1, 2, 3),
                     __builtin_shufflevector(q6, q7, 0, 1, 2, 3),
                     0, 1, 2, 3, 4, 5, 6, 7);
        };

        int s = 1;
        for (; s + 3 < len; s += 4) {
            // prefetch raw feats rows s+8..s+11 (consumed 8 steps later)
            float n0, n1, n2, n3;
            {
                int r0 = s + 8, r1 = s + 9, r2 = s + 10, r3 = s + 11;
                if (r0 > SS - 1) r0 = SS - 1;
                if (r1 > SS - 1) r1 = SS - 1;
                if (r2 > SS - 1) r2 = SS - 1;
                if (r3 > SS - 1) r3 = SS - 1;
                n0 = frow[(size_t)r0 * TT + lane];
                n1 = frow[(size_t)r1 * TT + lane];
                n2 = frow[(size_t)r2 * TT + lane];
                n3 = frow[(size_t)r3 * TT + lane];
            }
            // fe rows s+4..s+7 (read next iteration; disjoint mod 8 from s..s+3)
            febuf[(s + 4) & 7][lane] =
                (_Float16)__builtin_amdgcn_exp2f(fr[4] * LOG2E);
            febuf[(s + 5) & 7][lane] =
                (_Float16)__builtin_amdgcn_exp2f(fr[5] * LOG2E);
            febuf[(s + 6) & 7][lane] =
                (_Float16)__builtin_amdgcn_exp2f(fr[6] * LOG2E);
            febuf[(s + 7) & 7][lane] =
                (_Float16)__builtin_amdgcn_exp2f(fr[7] * LOG2E);

            step(s); step(s + 1); step(s + 2); step(s + 3);

            #pragma unroll
            for (int j = 0; j < 4; ++j) fr[j] = fr[j + 4];
            fr[4] = n0; fr[5] = n1; fr[6] = n2; fr[7] = n3;
        }

        // tail: fe rows s..s+2 were written by the last full iteration
        const int rem = len - s;   // 0..3
        if (rem > 0) step(s);
        if (rem > 1) step(s + 1);
        if (rem > 2) step(s + 2);

        // final transition to STOP: sum_from E[from] * exp(trans[from,STOP])
        float e = 0.f;
        #pragma unroll
        for (int sl = 0; sl < 8; ++sl) {
            const int t0 = 16 * g + sl, t1 = t0 + 8;
            e += (float)B0[sl] * __builtin_amdgcn_exp2f(
                     trans[t0 * TT + STOP_TAG] * LOG2E);
            e += (float)B1[sl] * __builtin_amdgcn_exp2f(
                     trans[t1 * TT + STOP_TAG] * LOG2E);
        }
        // values replicated within a group; reduce across the 4 groups
        e += __shfl_xor(e, 16);
        e += __shfl_xor(e, 32);

        if (lane == 0)
            atomicAdd(out, offs + (float)ksum * LN2
                           + LN2 * __builtin_amdgcn_logf(e));
    } else {
        // ---------------- gold score, wave 1 of the block --------------------
        const int* trow = tags + b * SS;
        int   cnt = 0;
        float acc = 0.f;
        for (int s = lane; s < SS; s += 64) {
            if (mrow[s] != 0) {
                ++cnt;
                const int tag  = trow[s];
                const int prev = (s == 0) ? START_TAG : trow[s - 1];
                acc += frow[(size_t)s * TT + tag] + trans[prev * TT + tag];
            }
        }
        #pragma unroll
        for (int off = 32; off; off >>= 1) {
            acc += __shfl_xor(acc, off);
            cnt += __shfl_xor(cnt, off);
        }
        if (lane == 0) {
            const int end_id = trow[cnt - 1];
            atomicAdd(out, -(acc + trans[end_id * TT + STOP_TAG]));
        }
    }
}

extern "C" void kernel_launch(void* const* d_in, const int* in_sizes, int n_in,
                              void* d_out, int out_size, void* d_ws, size_t ws_size,
                              hipStream_t stream) {
    const float* feats = (const float*)d_in[0];   // (B,S,T) f32
    const int*   mask  = (const int*)d_in[1];     // (B,S)   int (0/1)
    const int*   tags  = (const int*)d_in[2];     // (B,S)   int
    const float* trans = (const float*)d_in[3];   // (T,T)   f32
    float* out = (float*)d_out;

    (void)hipMemsetAsync(out, 0, sizeof(float), stream);
    crf_main<<<BB, 128, 0, stream>>>(feats, mask, tags, trans, out);
}